// Round 16
// baseline (134.261 us; speedup 1.0000x reference)
//
#include <hip/hip_runtime.h>

// Shapes fixed by the reference: N=M=512, B=1, C=256, H=8, Dh=32, fp32.

// DPP-based add-exchange (pure VALU, avoids ds_swizzle / LDS pipe).
template <int CTRL, int RMASK>
__device__ __forceinline__ float dpp_add(float v) {
  int x = __builtin_amdgcn_update_dpp(0, __float_as_int(v), CTRL, RMASK, 0xf, false);
  return v + __int_as_float(x);
}

// Nontemporal float4 load/store. __builtin_nontemporal_load rejects HIP's
// struct-wrapped float4; use a native clang ext_vector_type instead.
typedef float f32x4v __attribute__((ext_vector_type(4)));
__device__ __forceinline__ float4 nt_load4(const float* p) {
  f32x4v r = __builtin_nontemporal_load((const f32x4v*)p);
  return make_float4(r.x, r.y, r.z, r.w);
}
__device__ __forceinline__ void nt_store(float* p, float v) {
  __builtin_nontemporal_store(v, p);
}

// ---------------- Kernel 1: transpose Wq/Wk/Wv (256x256 each) ----------------
__global__ __launch_bounds__(256) void k_transpose(const float* __restrict__ Wq,
                                                   const float* __restrict__ Wk,
                                                   const float* __restrict__ Wv,
                                                   float* __restrict__ wt) {
  const float* W = (blockIdx.y == 0) ? Wq : (blockIdx.y == 1) ? Wk : Wv;
  float* O = wt + (size_t)blockIdx.y * 65536;
  __shared__ float t[64][65];
  const int tile = blockIdx.x;
  const int tr = (tile >> 2) * 64, tc = (tile & 3) * 64;
  const int c = threadIdx.x & 63, r0 = threadIdx.x >> 6;
#pragma unroll
  for (int i = 0; i < 16; ++i) {
    int r = r0 + i * 4;
    t[r][c] = W[(tr + r) * 256 + tc + c];
  }
  __syncthreads();
#pragma unroll
  for (int i = 0; i < 16; ++i) {
    int r = r0 + i * 4;
    O[(tc + r) * 256 + tr + c] = t[c][r];  // O[a][b] = W[b][a]
  }
}

// ---------------- Kernel 2: projections q,k,v = x @ W^T + b ----------------
__global__ __launch_bounds__(256) void k_proj(const float* __restrict__ q_in,
                                              const float* __restrict__ k_in,
                                              const float* __restrict__ v_in,
                                              const float* __restrict__ bq,
                                              const float* __restrict__ bk,
                                              const float* __restrict__ bv,
                                              const float* __restrict__ wt,
                                              float* __restrict__ outb) {
  const int mat = blockIdx.y;
  const float* x = mat == 0 ? q_in : mat == 1 ? k_in : v_in;
  const float* b = mat == 0 ? bq : mat == 1 ? bk : bv;
  const float* WT = wt + (size_t)mat * 65536;
  float* out = outb + (size_t)mat * 131072;

  __shared__ float xl[8][256];
  const int tid = threadIdx.x;
  const int n0 = blockIdx.x * 8;
  for (int idx = tid; idx < 2048; idx += 256)
    xl[idx >> 8][idx & 255] = x[(n0 + (idx >> 8)) * 256 + (idx & 255)];
  __syncthreads();

  float acc[8] = {0.f, 0.f, 0.f, 0.f, 0.f, 0.f, 0.f, 0.f};
  for (int j = 0; j < 256; j += 4) {
    const float w0 = WT[(j + 0) * 256 + tid];
    const float w1 = WT[(j + 1) * 256 + tid];
    const float w2 = WT[(j + 2) * 256 + tid];
    const float w3 = WT[(j + 3) * 256 + tid];
#pragma unroll
    for (int r = 0; r < 8; ++r) {
      const float4 xv = *(const float4*)&xl[r][j];
      acc[r] += xv.x * w0 + xv.y * w1 + xv.z * w2 + xv.w * w3;
    }
  }
  const float bb = b[tid];
#pragma unroll
  for (int r = 0; r < 8; ++r) out[(n0 + r) * 256 + tid] = acc[r] + bb;
}

// ---------------- Kernel 3: t[n][h][j] (pre-scaled by 1/sqrt(Dh)) ----------------
// qb (q.bg bias) dropped: constant over softmax axis -> shift-invariant.
__global__ __launch_bounds__(256) void k_tfold(const float* __restrict__ qkv,
                                               const float* __restrict__ Wg,
                                               float* __restrict__ t_ws) {
  const int h = blockIdx.y;
  const int n0 = blockIdx.x * 64;
  const int tid = threadIdx.x;
  const float scale = 0.17677669529663687f;  // 1/sqrt(32)
  __shared__ float wg_s[32][256];
  __shared__ float qs[64][32];

  for (int idx = tid; idx < 8192; idx += 256)
    wg_s[idx >> 8][idx & 255] = Wg[(size_t)(h * 32 + (idx >> 8)) * 256 + (idx & 255)];
  for (int idx = tid; idx < 2048; idx += 256)
    qs[idx >> 5][idx & 31] = qkv[(size_t)(n0 + (idx >> 5)) * 256 + h * 32 + (idx & 31)];
  __syncthreads();

  float wr[32];
#pragma unroll
  for (int i = 0; i < 32; ++i) wr[i] = wg_s[i][tid];
  for (int nn = 0; nn < 64; ++nn) {
    float a = 0.f;
#pragma unroll
    for (int i = 0; i < 32; ++i) a = fmaf(qs[nn][i], wr[i], a);
    t_ws[(size_t)(n0 + nn) * 2048 + h * 256 + tid] = a * scale;
  }
}

// ---------------- Kernel 4: FUSED (R10 structure) + nontemporal E/K/attn ----------------
// 512 threads = 8 waves. Stream: wave w owns m-rows [w*64, w*64+64), 2 rows/iter
// (one per 32-lane half); 32 lanes/row, 8 channels/lane; t fragment in 64 regs;
// K folded via select trick. E and K loads NONTEMPORAL: zero reuse, keep them
// from evicting k/v/t working set out of L1/L2 (pollution hypothesis). attn
// writes nontemporal (write-once). 5-step DPP reduce, cndmask gather, single
// predicated store. PV: float4 v loads, 8-way m-split, padded pv2 reduce.
__global__ __launch_bounds__(512, 4) void k_main(const float* __restrict__ Eg,
                                                 const float* __restrict__ qkv,
                                                 const float* __restrict__ t_ws,
                                                 float* __restrict__ out) {
  const float* k_g = qkv + 131072;
  const float* v_g = qkv + 262144;
  const int n = blockIdx.x;
  const int tid = threadIdx.x;
  const int lane = tid & 63, w = tid >> 6;
  const int s = lane & 31, g = lane >> 5;
  const int hd = s >> 2;  // head owning this lane's 8 channels
  const float scale = 0.17677669529663687f;  // 1/sqrt(32)
  float* attn = out + 131072;

  __shared__ float sc[8 * 520];   // [8 heads][520 stride] raw-then-exp scores
  __shared__ float invd[8];
  __shared__ float pv2[8 * 260];  // padded partial PV sums

  // t fragment: 8 heads x this lane's 8 channels (pre-scaled; L2-resident)
  float t_r[8][8];
#pragma unroll
  for (int h = 0; h < 8; ++h) {
    const float4 a = *(const float4*)(t_ws + (size_t)n * 2048 + h * 256 + s * 8);
    const float4 b = *(const float4*)(t_ws + (size_t)n * 2048 + h * 256 + s * 8 + 4);
    t_r[h][0] = a.x; t_r[h][1] = a.y; t_r[h][2] = a.z; t_r[h][3] = a.w;
    t_r[h][4] = b.x; t_r[h][5] = b.y; t_r[h][6] = b.z; t_r[h][7] = b.w;
  }
  // q fragment, pre-scaled (so kacc lands scaled)
  float q_r[8];
  {
    const float4 a = *(const float4*)(qkv + n * 256 + s * 8);
    const float4 b = *(const float4*)(qkv + n * 256 + s * 8 + 4);
    q_r[0] = a.x * scale; q_r[1] = a.y * scale; q_r[2] = a.z * scale; q_r[3] = a.w * scale;
    q_r[4] = b.x * scale; q_r[5] = b.y * scale; q_r[6] = b.z * scale; q_r[7] = b.w * scale;
  }

  // ---- stream phase: rows w*64 + it*2 + g ----
  const float* E0 = Eg + ((size_t)n * 512 + w * 64 + g) * 256 + s * 8;
  const float* K0 = k_g + (size_t)(w * 64 + g) * 256 + s * 8;

#pragma unroll 4
  for (int it = 0; it < 32; ++it) {
    const float4 e0 = nt_load4(E0);
    const float4 e1 = nt_load4(E0 + 4);
    const float4 k0 = nt_load4(K0);
    const float4 k1 = nt_load4(K0 + 4);
    // k-dot partial: this lane's channels all belong to head hd
    float kacc;
    kacc = k0.x * q_r[0];             kacc = fmaf(k0.y, q_r[1], kacc);
    kacc = fmaf(k0.z, q_r[2], kacc);  kacc = fmaf(k0.w, q_r[3], kacc);
    kacc = fmaf(k1.x, q_r[4], kacc);  kacc = fmaf(k1.y, q_r[5], kacc);
    kacc = fmaf(k1.z, q_r[6], kacc);  kacc = fmaf(k1.w, q_r[7], kacc);
    const int m = w * 64 + it * 2 + g;
    float vout = 0.f;
#pragma unroll
    for (int h = 0; h < 8; ++h) {
      float v = (hd == h) ? kacc : 0.f;   // loop-invariant mask -> cndmask
      v = fmaf(e0.x, t_r[h][0], v); v = fmaf(e0.y, t_r[h][1], v);
      v = fmaf(e0.z, t_r[h][2], v); v = fmaf(e0.w, t_r[h][3], v);
      v = fmaf(e1.x, t_r[h][4], v); v = fmaf(e1.y, t_r[h][5], v);
      v = fmaf(e1.z, t_r[h][6], v); v = fmaf(e1.w, t_r[h][7], v);
      // 32-lane reduce: xor1, xor2, half_mirror(xor4), mirror(xor8),
      // bcast15 folds row0 into row1 (valid in lanes 16-31 / 48-63).
      v = dpp_add<0xB1, 0xf>(v);
      v = dpp_add<0x4E, 0xf>(v);
      v = dpp_add<0x141, 0xf>(v);
      v = dpp_add<0x140, 0xf>(v);
      v = dpp_add<0x142, 0xa>(v);
      vout = (s == 16 + h) ? v : vout;    // loop-invariant mask -> cndmask
    }
    // single predicated store: lanes 16-23 (row m, g=0) and 48-55 (row m+1, g=1)
    if ((unsigned)(s - 16) < 8u) sc[(s - 16) * 520 + m] = vout;
    E0 += 512; K0 += 512;
  }
  __syncthreads();

  // ---- softmax over m for head w ----
  {
    float vals[8];
#pragma unroll
    for (int i = 0; i < 8; ++i) vals[i] = sc[w * 520 + lane + i * 64];
    float mx = vals[0];
#pragma unroll
    for (int i = 1; i < 8; ++i) mx = fmaxf(mx, vals[i]);
#pragma unroll
    for (int off = 1; off < 64; off <<= 1) mx = fmaxf(mx, __shfl_xor(mx, off));
    float sum = 0.f;
#pragma unroll
    for (int i = 0; i < 8; ++i) {
      const float e = __expf(vals[i] - mx);
      sum += e;
      sc[w * 520 + lane + i * 64] = e;
    }
#pragma unroll
    for (int off = 1; off < 64; off <<= 1) sum += __shfl_xor(sum, off);
    if (lane == 0) invd[w] = 1.f / sum;
  }
  __syncthreads();

  // ---- normalized attn write (nontemporal: written once, never re-read) ----
#pragma unroll
  for (int r = 0; r < 8; ++r) {
    const int idx = tid + r * 512;
    const int h = idx >> 9, mm = idx & 511;
    nt_store(&attn[(size_t)h * 262144 + n * 512 + mm], sc[h * 520 + mm] * invd[h]);
  }

  // ---- PV: thread covers c4..c4+3 (float4 v loads), m-chunk mc of 64 rows ----
  {
    const int c4 = (tid & 63) * 4;       // 0..252
    const int mc = tid >> 6;             // 0..7 (uniform per wave)
    const int hh = (tid & 63) >> 3;      // head of c4..c4+3
    const float* pr = sc + hh * 520 + mc * 64;
    const float* vp = v_g + (size_t)(mc * 64) * 256 + c4;
    float4 a4 = {0.f, 0.f, 0.f, 0.f};
#pragma unroll 4
    for (int m = 0; m < 64; ++m) {
      const float p = pr[m];
      const float4 v4 = *(const float4*)vp;
      a4.x = fmaf(p, v4.x, a4.x);
      a4.y = fmaf(p, v4.y, a4.y);
      a4.z = fmaf(p, v4.z, a4.z);
      a4.w = fmaf(p, v4.w, a4.w);
      vp += 256;
    }
    *(float4*)&pv2[mc * 260 + c4] = a4;
  }
  __syncthreads();
  if (tid < 256) {
    float acc = 0.f;
#pragma unroll
    for (int mc2 = 0; mc2 < 8; ++mc2) acc += pv2[mc2 * 260 + tid];
    out[n * 256 + tid] = acc * invd[tid >> 5];
  }
}

extern "C" void kernel_launch(void* const* d_in, const int* in_sizes, int n_in,
                              void* d_out, int out_size, void* d_ws, size_t ws_size,
                              hipStream_t stream) {
  const float* query = (const float*)d_in[0];
  const float* key   = (const float*)d_in[1];
  const float* value = (const float*)d_in[2];
  const float* Eg    = (const float*)d_in[3];
  const float* Wq    = (const float*)d_in[4];
  const float* bq    = (const float*)d_in[5];
  const float* Wk    = (const float*)d_in[6];
  const float* bk    = (const float*)d_in[7];
  const float* Wv    = (const float*)d_in[8];
  const float* bv    = (const float*)d_in[9];
  const float* Wg    = (const float*)d_in[10];
  float* out = (float*)d_out;

  // ws layout (floats): wt[3*65536] | qkv[3*131072] | t_ws[512*2048]  ≈ 6.5 MB
  float* ws = (float*)d_ws;
  float* wt = ws;
  float* qkv = wt + 3 * 65536;
  float* t_ws = qkv + 3 * 131072;

  k_transpose<<<dim3(16, 3), 256, 0, stream>>>(Wq, Wk, Wv, wt);
  k_proj<<<dim3(64, 3), 256, 0, stream>>>(query, key, value, bq, bk, bv, wt, qkv);
  k_tfold<<<dim3(8, 8), 256, 0, stream>>>(qkv, Wg, t_ws);
  k_main<<<dim3(512), 512, 0, stream>>>(Eg, qkv, t_ws, out);
}

// Round 17
// 95.553 us; speedup vs baseline: 1.4051x; 1.4051x over previous
//
#include <hip/hip_runtime.h>

// Shapes fixed by the reference: N=M=512, B=1, C=256, H=8, Dh=32, fp32.

// DPP-based add-exchange (pure VALU, avoids ds_swizzle / LDS pipe).
template <int CTRL, int RMASK>
__device__ __forceinline__ float dpp_add(float v) {
  int x = __builtin_amdgcn_update_dpp(0, __float_as_int(v), CTRL, RMASK, 0xf, false);
  return v + __int_as_float(x);
}

// ---------------- Kernel 1: projections q,k,v = x @ W^T + b (in-kernel transpose) ----------------
// Stages W[0:256][j0:j0+32] tiles in LDS (coalesced row reads, +1 pad ->
// conflict-free column access). Eliminates the separate transpose kernel and
// the wt workspace round-trip.
__global__ __launch_bounds__(256) void k_proj(const float* __restrict__ q_in,
                                              const float* __restrict__ k_in,
                                              const float* __restrict__ v_in,
                                              const float* __restrict__ bq,
                                              const float* __restrict__ bk,
                                              const float* __restrict__ bv,
                                              const float* __restrict__ Wq,
                                              const float* __restrict__ Wk,
                                              const float* __restrict__ Wv,
                                              float* __restrict__ outb) {
  const int mat = blockIdx.y;
  const float* x = mat == 0 ? q_in : mat == 1 ? k_in : v_in;
  const float* b = mat == 0 ? bq : mat == 1 ? bk : bv;
  const float* W = mat == 0 ? Wq : mat == 1 ? Wk : Wv;
  float* out = outb + (size_t)mat * 131072;

  __shared__ float xl[8][256];
  __shared__ float wtile[256][33];  // +1 pad: column reads conflict-free
  const int tid = threadIdx.x;
  const int n0 = blockIdx.x * 8;
  for (int idx = tid; idx < 2048; idx += 256)
    xl[idx >> 8][idx & 255] = x[(n0 + (idx >> 8)) * 256 + (idx & 255)];

  float acc[8] = {0.f, 0.f, 0.f, 0.f, 0.f, 0.f, 0.f, 0.f};
  for (int j0 = 0; j0 < 256; j0 += 32) {
    __syncthreads();  // first iter: xl ready; later: wtile readers done
    for (int idx = tid; idx < 8192; idx += 256) {
      const int cc = idx >> 5, jj = idx & 31;
      wtile[cc][jj] = W[cc * 256 + j0 + jj];
    }
    __syncthreads();
#pragma unroll
    for (int jj = 0; jj < 32; jj += 4) {
      const float w0 = wtile[tid][jj + 0];
      const float w1 = wtile[tid][jj + 1];
      const float w2 = wtile[tid][jj + 2];
      const float w3 = wtile[tid][jj + 3];
#pragma unroll
      for (int r = 0; r < 8; ++r) {
        const float4 xv = *(const float4*)&xl[r][j0 + jj];
        acc[r] += xv.x * w0 + xv.y * w1 + xv.z * w2 + xv.w * w3;
      }
    }
  }
  const float bb = b[tid];
#pragma unroll
  for (int r = 0; r < 8; ++r) out[(n0 + r) * 256 + tid] = acc[r] + bb;
}

// ---------------- Kernel 2: FUSED t-fold + scores + softmax + attn + attn@v ----------------
// One block per n, 512 threads = 8 waves.
// Prologue: t[n][h][j] = sum_i q[n,i]*Wg[i,j] (pre-scaled) computed IN-BLOCK
//   into LDS (0.5 GFLOP chip-wide; Wg is L2-hot, shared by all 512 blocks) —
//   eliminates the k_tfold kernel and the 4 MB t_ws round-trip. qb dropped
//   (softmax shift-invariance).
// Stream (R10 structure, best measured 105.2): wave w owns m-rows
//   [w*64, w*64+64), 2 rows/iter; 32 lanes/row, 8 ch/lane; t fragment 64 regs;
//   K folded via select trick; 5-step DPP reduce; cndmask gather; single
//   predicated store. PLAIN loads (R16: nontemporal hurt — L3 assist matters).
// Epilogue: softmax per head per wave; attn write; PV float4 v-loads.
__global__ __launch_bounds__(512, 4) void k_main(const float* __restrict__ Eg,
                                                 const float* __restrict__ qkv,
                                                 const float* __restrict__ Wg,
                                                 float* __restrict__ out) {
  const float* k_g = qkv + 131072;
  const float* v_g = qkv + 262144;
  const int n = blockIdx.x;
  const int tid = threadIdx.x;
  const int lane = tid & 63, w = tid >> 6;
  const int s = lane & 31, g = lane >> 5;
  const int hd = s >> 2;  // head owning this lane's 8 channels
  const float scale = 0.17677669529663687f;  // 1/sqrt(32)
  float* attn = out + 131072;

  __shared__ float ql[256];       // q[n]
  __shared__ float t_lds[2048];   // [8 heads][256 j], pre-scaled
  __shared__ float sc[8 * 520];   // [8 heads][520 stride] raw-then-exp scores
  __shared__ float invd[8];
  __shared__ float pv2[8 * 260];  // padded partial PV sums

  // ---- prologue: q -> LDS, then t-fold into t_lds ----
  if (tid < 256) ql[tid] = qkv[n * 256 + tid];
  __syncthreads();
  {
    const int jcol = tid & 255, hb = (tid >> 8) * 4;  // thread: col j, 4 heads
#pragma unroll
    for (int hh = 0; hh < 4; ++hh) {
      const int h = hb + hh;
      float a = 0.f;
      const float* wg = Wg + (size_t)(h * 32) * 256 + jcol;
#pragma unroll 8
      for (int i = 0; i < 32; ++i) a = fmaf(ql[h * 32 + i], wg[(size_t)i * 256], a);
      t_lds[h * 256 + jcol] = a * scale;
    }
  }
  __syncthreads();

  // t fragment: 8 heads x this lane's 8 channels
  float t_r[8][8];
#pragma unroll
  for (int h = 0; h < 8; ++h) {
#pragma unroll
    for (int c = 0; c < 8; ++c) t_r[h][c] = t_lds[h * 256 + s * 8 + c];
  }
  // q fragment, pre-scaled (so kacc lands scaled)
  float q_r[8];
#pragma unroll
  for (int c = 0; c < 8; ++c) q_r[c] = ql[s * 8 + c] * scale;

  // ---- stream phase: rows w*64 + it*2 + g ----
  const float* E0 = Eg + ((size_t)n * 512 + w * 64 + g) * 256 + s * 8;
  const float* K0 = k_g + (size_t)(w * 64 + g) * 256 + s * 8;

#pragma unroll 4
  for (int it = 0; it < 32; ++it) {
    const float4 e0 = *(const float4*)(E0);
    const float4 e1 = *(const float4*)(E0 + 4);
    const float4 k0 = *(const float4*)(K0);
    const float4 k1 = *(const float4*)(K0 + 4);
    // k-dot partial: this lane's channels all belong to head hd
    float kacc;
    kacc = k0.x * q_r[0];             kacc = fmaf(k0.y, q_r[1], kacc);
    kacc = fmaf(k0.z, q_r[2], kacc);  kacc = fmaf(k0.w, q_r[3], kacc);
    kacc = fmaf(k1.x, q_r[4], kacc);  kacc = fmaf(k1.y, q_r[5], kacc);
    kacc = fmaf(k1.z, q_r[6], kacc);  kacc = fmaf(k1.w, q_r[7], kacc);
    const int m = w * 64 + it * 2 + g;
    float vout = 0.f;
#pragma unroll
    for (int h = 0; h < 8; ++h) {
      float v = (hd == h) ? kacc : 0.f;   // loop-invariant mask -> cndmask
      v = fmaf(e0.x, t_r[h][0], v); v = fmaf(e0.y, t_r[h][1], v);
      v = fmaf(e0.z, t_r[h][2], v); v = fmaf(e0.w, t_r[h][3], v);
      v = fmaf(e1.x, t_r[h][4], v); v = fmaf(e1.y, t_r[h][5], v);
      v = fmaf(e1.z, t_r[h][6], v); v = fmaf(e1.w, t_r[h][7], v);
      // 32-lane reduce: xor1, xor2, half_mirror(xor4), mirror(xor8),
      // bcast15 folds row0 into row1 (valid in lanes 16-31 / 48-63).
      v = dpp_add<0xB1, 0xf>(v);
      v = dpp_add<0x4E, 0xf>(v);
      v = dpp_add<0x141, 0xf>(v);
      v = dpp_add<0x140, 0xf>(v);
      v = dpp_add<0x142, 0xa>(v);
      vout = (s == 16 + h) ? v : vout;    // loop-invariant mask -> cndmask
    }
    // single predicated store: lanes 16-23 (row m, g=0) and 48-55 (row m+1, g=1)
    if ((unsigned)(s - 16) < 8u) sc[(s - 16) * 520 + m] = vout;
    E0 += 512; K0 += 512;
  }
  __syncthreads();

  // ---- softmax over m for head w ----
  {
    float vals[8];
#pragma unroll
    for (int i = 0; i < 8; ++i) vals[i] = sc[w * 520 + lane + i * 64];
    float mx = vals[0];
#pragma unroll
    for (int i = 1; i < 8; ++i) mx = fmaxf(mx, vals[i]);
#pragma unroll
    for (int off = 1; off < 64; off <<= 1) mx = fmaxf(mx, __shfl_xor(mx, off));
    float sum = 0.f;
#pragma unroll
    for (int i = 0; i < 8; ++i) {
      const float e = __expf(vals[i] - mx);
      sum += e;
      sc[w * 520 + lane + i * 64] = e;
    }
#pragma unroll
    for (int off = 1; off < 64; off <<= 1) sum += __shfl_xor(sum, off);
    if (lane == 0) invd[w] = 1.f / sum;
  }
  __syncthreads();

  // ---- normalized attn write ----
#pragma unroll
  for (int r = 0; r < 8; ++r) {
    const int idx = tid + r * 512;
    const int h = idx >> 9, mm = idx & 511;
    attn[(size_t)h * 262144 + n * 512 + mm] = sc[h * 520 + mm] * invd[h];
  }

  // ---- PV: thread covers c4..c4+3 (float4 v loads), m-chunk mc of 64 rows ----
  {
    const int c4 = (tid & 63) * 4;       // 0..252
    const int mc = tid >> 6;             // 0..7 (uniform per wave)
    const int hh = (tid & 63) >> 3;      // head of c4..c4+3
    const float* pr = sc + hh * 520 + mc * 64;
    const float* vp = v_g + (size_t)(mc * 64) * 256 + c4;
    float4 a4 = {0.f, 0.f, 0.f, 0.f};
#pragma unroll 4
    for (int m = 0; m < 64; ++m) {
      const float p = pr[m];
      const float4 v4 = *(const float4*)vp;
      a4.x = fmaf(p, v4.x, a4.x);
      a4.y = fmaf(p, v4.y, a4.y);
      a4.z = fmaf(p, v4.z, a4.z);
      a4.w = fmaf(p, v4.w, a4.w);
      vp += 256;
    }
    *(float4*)&pv2[mc * 260 + c4] = a4;
  }
  __syncthreads();
  if (tid < 256) {
    float acc = 0.f;
#pragma unroll
    for (int mc2 = 0; mc2 < 8; ++mc2) acc += pv2[mc2 * 260 + tid];
    out[n * 256 + tid] = acc * invd[tid >> 5];
  }
}

extern "C" void kernel_launch(void* const* d_in, const int* in_sizes, int n_in,
                              void* d_out, int out_size, void* d_ws, size_t ws_size,
                              hipStream_t stream) {
  const float* query = (const float*)d_in[0];
  const float* key   = (const float*)d_in[1];
  const float* value = (const float*)d_in[2];
  const float* Eg    = (const float*)d_in[3];
  const float* Wq    = (const float*)d_in[4];
  const float* bq    = (const float*)d_in[5];
  const float* Wk    = (const float*)d_in[6];
  const float* bk    = (const float*)d_in[7];
  const float* Wv    = (const float*)d_in[8];
  const float* bv    = (const float*)d_in[9];
  const float* Wg    = (const float*)d_in[10];
  float* out = (float*)d_out;

  // ws layout (floats): qkv[3*131072]  = 1.5 MB
  float* qkv = (float*)d_ws;

  k_proj<<<dim3(64, 3), 256, 0, stream>>>(query, key, value, bq, bk, bv, Wq, Wk, Wv, qkv);
  k_main<<<dim3(512), 512, 0, stream>>>(Eg, qkv, Wg, out);
}